// Round 4
// baseline (390.362 us; speedup 1.0000x reference)
//
#include <hip/hip_runtime.h>
#include <hip/hip_bf16.h>
#include <stdint.h>

typedef __attribute__((ext_vector_type(4))) float f32x4;
typedef __attribute__((ext_vector_type(8))) short bf16x8;
typedef __attribute__((ext_vector_type(4))) float float4v;

static constexpr int KD    = 1024;   // hidden dim
static constexpr int ND    = 2048;   // expert out dim (gate+up)
static constexpr int NE    = 8;      // experts
static constexpr int MROWS = 16384;  // hidden rows
static constexpr int RFLAT = 32768;  // M * topk
static constexpr int OUTN  = 1024;   // output cols (ND/2)

// ws ints: cnt[8]@0, cursor[8]@8, offs[9]@16, mode@31, tileoff[9]@40
static constexpr size_t WS_ROWLIST = 1024;
static constexpr size_t WS_HB      = 262144;
static constexpr size_t WS_WT      = 262144 + (size_t)33554432;

__device__ __forceinline__ unsigned short f2bf(float f) {
  uint32_t u = __float_as_uint(f);
  uint32_t r = (u + 0x7FFFu + ((u >> 16) & 1u)) >> 16;
  return (unsigned short)r;
}

__device__ __forceinline__ void gload16(const void* g, void* l) {
  __builtin_amdgcn_global_load_lds(
      (__attribute__((address_space(1))) void*)(void*)g,
      (__attribute__((address_space(3))) void*)l, 16, 0, 0);
}

// Detect int32-converted vs raw-int64 ids (odd 32-bit slots all zero => int64).
__global__ void k_detect(const int* __restrict__ ids32, int* __restrict__ wsi) {
  int t = blockIdx.x * 256 + threadIdx.x;
  int i = 2 * t + 1;
  if (i < RFLAT && ids32[i] != 0) atomicOr(&wsi[31], 1);
}

__device__ __forceinline__ int read_id(const int* ids32, int t, int mode) {
  return (mode ? ids32[t] : ids32[2 * t]) & 7;
}

// LDS-histogram count: 64 blocks x 512 elems -> 512 global atomics.
__global__ void k_count(const int* __restrict__ ids, int* __restrict__ wsi) {
  __shared__ int h[8];
  const int tid = threadIdx.x;
  if (tid < 8) h[tid] = 0;
  __syncthreads();
  const int mode = wsi[31];
  const int base = blockIdx.x * 512 + tid;
  atomicAdd(&h[read_id(ids, base, mode)], 1);
  atomicAdd(&h[read_id(ids, base + 256, mode)], 1);
  __syncthreads();
  if (tid < 8 && h[tid]) atomicAdd(&wsi[tid], h[tid]);
}

__global__ void k_scan(int* wsi) {
  if (threadIdx.x == 0) {
    int o = 0, to = 0;
    for (int e = 0; e < NE; ++e) {
      int c = wsi[e];
      wsi[16 + e] = o;   // offs
      wsi[8 + e]  = o;   // cursor
      wsi[40 + e] = to;  // tile offset (256-row tiles)
      o += c;
      to += (c + 255) / 256;
    }
    wsi[16 + NE] = o;
    wsi[40 + NE] = to;
  }
}

// LDS-histogram scatter: per-block base + local rank.
__global__ void k_scatter(const int* __restrict__ ids, int* __restrict__ wsi,
                          int* __restrict__ rowlist) {
  __shared__ int h[8], base[8], c2[8];
  const int tid = threadIdx.x;
  if (tid < 8) { h[tid] = 0; c2[tid] = 0; }
  __syncthreads();
  const int mode = wsi[31];
  const int t = blockIdx.x * 256 + tid;
  const int e = read_id(ids, t, mode);
  atomicAdd(&h[e], 1);
  __syncthreads();
  if (tid < 8 && h[tid]) base[tid] = atomicAdd(&wsi[8 + tid], h[tid]);
  __syncthreads();
  const int r = atomicAdd(&c2[e], 1);
  rowlist[base[e] + r] = t;
}

__global__ void k_cvtH(const float* __restrict__ H, unsigned short* __restrict__ Hb) {
  const int n4 = (MROWS * KD) / 4;
  const int stride = gridDim.x * blockDim.x;
  for (int i = blockIdx.x * blockDim.x + threadIdx.x; i < n4; i += stride) {
    float4v v = ((const float4v*)H)[i];
    ushort4 o;
    o.x = f2bf(v.x); o.y = f2bf(v.y); o.z = f2bf(v.z); o.w = f2bf(v.w);
    ((ushort4*)Hb)[i] = o;
  }
}

// Transpose + convert: W[e][k][n] fp32 -> Wt[e][n][k] bf16 (64x64 tiles).
__global__ void k_cvtW(const float* __restrict__ W, unsigned short* __restrict__ Wt) {
  __shared__ float tile[64][65];
  const int e  = blockIdx.z;
  const int n0 = blockIdx.x * 64;
  const int k0 = blockIdx.y * 64;
  const int tx = threadIdx.x, ty = threadIdx.y;
  const float* Wp = W + (size_t)e * KD * ND;
  #pragma unroll
  for (int i = ty; i < 64; i += 8)
    tile[i][tx] = Wp[(size_t)(k0 + i) * ND + n0 + tx];
  __syncthreads();
  unsigned short* Wo = Wt + (size_t)e * ND * KD;
  #pragma unroll
  for (int i = ty; i < 64; i += 8)
    Wo[(size_t)(n0 + i) * KD + k0 + tx] = f2bf(tile[tx][i]);
}

// Grouped GEMM, 2-phase double-buffered (T3-minimum recipe):
// 256 gathered rows x 256 weight-cols (128 gate + 128 up), BK=64, 512 threads
// = 8 waves (2M x 4N), wave tile 128 rows x 64 wcols, acc[8][4].
// LDS 128 KiB: A[2][8kc][256row][16B] @0, B[2][8kc][256col][16B] @64KiB.
// Per K-step: prefetch next tile into buf^1, ds_read+64 MFMA on buf, ONE
// barrier (compiler's vmcnt(0)+lgkmcnt(0) drain) -> load latency hides under
// the whole compute phase. Gate/up interleaved per wave-col group so the
// silu epilogue pairs in-register.
__global__ __launch_bounds__(512, 2) void k_gemm(
    const unsigned short* __restrict__ Hb, const unsigned short* __restrict__ Wt,
    const int* __restrict__ wsi, const int* __restrict__ rowlist,
    float* __restrict__ Out) {
  const int bid = blockIdx.x;
  const int xcd = bid & 7;
  const int j   = bid >> 3;
  const int colblk = j & 7;        // col-blocks fastest within an XCD: A-tile L2-resident
  const int rt  = xcd + (j >> 3) * 8;
  if (rt >= wsi[48]) return;
  int e = 0;
  #pragma unroll
  for (int q = 1; q < 8; ++q)
    if (rt >= wsi[40 + q]) e = q;
  const int cnt = wsi[e];
  const int tile_base = (rt - wsi[40 + e]) * 256;
  const int tile_cnt = min(256, cnt - tile_base);
  const int off = wsi[16 + e] + tile_base;
  const int c0 = colblk * 128;     // out-col base

  __shared__ char lds[131072];

  const int t = threadIdx.x;

  // A staging: row = t&255 (flat row -> hidden row >>1), khalf = t>>8.
  const int arow = t & 255;
  const int rid_a = rowlist[off + min(arow, tile_cnt - 1)];
  const char* srcA = (const char*)Hb + (size_t)(rid_a >> 1) * (KD * 2) + ((t >> 8) * 16);
  // B staging: LDS col lcol = t&255 maps to weight col (gate/up interleaved
  // per 64-col wave group: h<2 gate, h>=2 up).
  const int lcol = t & 255;
  const int wn_s = lcol >> 6, r64 = lcol & 63;
  const int h_s = r64 >> 4, l_s = r64 & 15;
  const int wcol = (h_s < 2) ? (c0 + wn_s * 32 + h_s * 16 + l_s)
                             : (OUTN + c0 + wn_s * 32 + (h_s - 2) * 16 + l_s);
  const char* srcB = (const char*)Wt + ((size_t)e * ND + wcol) * (KD * 2) + ((t >> 8) * 16);

  char* dA = lds + t * 16;          // + buf*32768 + u*8192
  char* dB = lds + 65536 + t * 16;  // + buf*32768 + u*8192

  const int lane = t & 63, wid = t >> 6;
  const int wm = wid >> 2, wn = wid & 3;
  const int kc = lane >> 4, l15 = lane & 15;

  f32x4 acc[8][4];
  #pragma unroll
  for (int m = 0; m < 8; ++m)
    #pragma unroll
    for (int h = 0; h < 4; ++h)
      acc[m][h] = (f32x4){0.f, 0.f, 0.f, 0.f};

  int aoff[2][8], boff[2][4];
  #pragma unroll
  for (int q = 0; q < 2; ++q) {
    #pragma unroll
    for (int m = 0; m < 8; ++m)
      aoff[q][m] = (q * 4 + kc) * 4096 + (wm * 128 + m * 16 + l15) * 16;
    #pragma unroll
    for (int h = 0; h < 4; ++h)
      boff[q][h] = 65536 + (q * 4 + kc) * 4096 + (wn * 64 + h * 16 + l15) * 16;
  }

  // Prologue: stage K-tile 0 into buf0.
  #pragma unroll
  for (int u = 0; u < 4; ++u) {
    gload16(srcA + u * 32, dA + u * 8192);
    gload16(srcB + u * 32, dB + u * 8192);
  }
  __syncthreads();

  int cur = 0;
  for (int ks = 0; ks < KD / 64; ++ks) {
    if (ks < KD / 64 - 1) {   // prefetch next K-tile into the other buffer
      const size_t go = (size_t)(ks + 1) * 128;
      const int nb = (cur ^ 1) * 32768;
      #pragma unroll
      for (int u = 0; u < 4; ++u) {
        gload16(srcA + go + u * 32, dA + nb + u * 8192);
        gload16(srcB + go + u * 32, dB + nb + u * 8192);
      }
    }
    const int cb = cur * 32768;
    #pragma unroll
    for (int q = 0; q < 2; ++q) {
      bf16x8 af[8], bfv[4];
      #pragma unroll
      for (int m = 0; m < 8; ++m) af[m] = *(const bf16x8*)(lds + cb + aoff[q][m]);
      #pragma unroll
      for (int h = 0; h < 4; ++h) bfv[h] = *(const bf16x8*)(lds + cb + boff[q][h]);
      #pragma unroll
      for (int m = 0; m < 8; ++m)
        #pragma unroll
        for (int h = 0; h < 4; ++h)
          acc[m][h] = __builtin_amdgcn_mfma_f32_16x16x32_bf16(af[m], bfv[h], acc[m][h], 0, 0, 0);
    }
    __syncthreads();
    cur ^= 1;
  }

  // Fused epilogue: gate = acc[m][h], up = acc[m][h+2], h in {0,1}.
  #pragma unroll
  for (int m = 0; m < 8; ++m) {
    const int rbase = wm * 128 + m * 16 + kc * 4;
    #pragma unroll
    for (int i = 0; i < 4; ++i) {
      const int rl = rbase + i;
      if (rl < tile_cnt) {
        const size_t orow = (size_t)rowlist[off + rl] * OUTN;
        #pragma unroll
        for (int h = 0; h < 2; ++h) {
          float g = acc[m][h][i];
          float u = acc[m][h + 2][i];
          float s = g / (1.0f + __expf(-g)) * u;
          Out[orow + c0 + wn * 32 + h * 16 + l15] = s;
        }
      }
    }
  }
}

extern "C" void kernel_launch(void* const* d_in, const int* in_sizes, int n_in,
                              void* d_out, int out_size, void* d_ws, size_t ws_size,
                              hipStream_t stream) {
  const float* H  = (const float*)d_in[0];
  const float* W  = (const float*)d_in[1];
  const int* ids  = (const int*)d_in[2];
  float* Out      = (float*)d_out;
  char* ws        = (char*)d_ws;
  int* wsi        = (int*)ws;
  int* rowlist    = (int*)(ws + WS_ROWLIST);
  unsigned short* Hb = (unsigned short*)(ws + WS_HB);
  unsigned short* Wt = (unsigned short*)(ws + WS_WT);

  hipMemsetAsync(ws, 0, 1024, stream);
  k_detect<<<RFLAT / 2 / 256, 256, 0, stream>>>(ids, wsi);
  k_count<<<RFLAT / 512, 256, 0, stream>>>(ids, wsi);
  k_scan<<<1, 64, 0, stream>>>(wsi);
  k_scatter<<<RFLAT / 256, 256, 0, stream>>>(ids, wsi, rowlist);
  k_cvtH<<<2048, 256, 0, stream>>>(H, Hb);
  k_cvtW<<<dim3(ND / 64, KD / 64, NE), dim3(64, 8), 0, stream>>>(W, Wt);
  // rowtiles (256-row) <= 135; 17 slots per XCD x 8 XCDs x 8 colblocks
  k_gemm<<<8 * 17 * 8, 512, 0, stream>>>(Hb, Wt, wsi, rowlist, Out);
}

// Round 5
// 243.315 us; speedup vs baseline: 1.6043x; 1.6043x over previous
//
#include <hip/hip_runtime.h>
#include <hip/hip_bf16.h>
#include <stdint.h>

typedef __attribute__((ext_vector_type(4))) float f32x4;
typedef __attribute__((ext_vector_type(8))) short bf16x8;
typedef __attribute__((ext_vector_type(4))) float float4v;

static constexpr int KD    = 1024;   // hidden dim
static constexpr int ND    = 2048;   // expert out dim (gate+up)
static constexpr int NE    = 8;      // experts
static constexpr int MROWS = 16384;  // hidden rows
static constexpr int RFLAT = 32768;  // M * topk
static constexpr int OUTN  = 1024;   // output cols (ND/2)

// ws ints: cnt[8]@0, cursor[8]@8, offs[9]@16, mode@31, tileoff[9]@40
static constexpr size_t WS_ROWLIST = 1024;
static constexpr size_t WS_HB      = 262144;
static constexpr size_t WS_WT      = 262144 + (size_t)33554432;

__device__ __forceinline__ unsigned short f2bf(float f) {
  uint32_t u = __float_as_uint(f);
  uint32_t r = (u + 0x7FFFu + ((u >> 16) & 1u)) >> 16;
  return (unsigned short)r;
}

__device__ __forceinline__ void gload16(const void* g, void* l) {
  __builtin_amdgcn_global_load_lds(
      (__attribute__((address_space(1))) void*)(void*)g,
      (__attribute__((address_space(3))) void*)l, 16, 0, 0);
}

// Detect int32-converted vs raw-int64 ids (odd 32-bit slots all zero => int64).
__global__ void k_detect(const int* __restrict__ ids32, int* __restrict__ wsi) {
  int t = blockIdx.x * 256 + threadIdx.x;
  int i = 2 * t + 1;
  if (i < RFLAT && ids32[i] != 0) atomicOr(&wsi[31], 1);
}

__device__ __forceinline__ int read_id(const int* ids32, int t, int mode) {
  return (mode ? ids32[t] : ids32[2 * t]) & 7;
}

// LDS-histogram count.
__global__ void k_count(const int* __restrict__ ids, int* __restrict__ wsi) {
  __shared__ int h[8];
  const int tid = threadIdx.x;
  if (tid < 8) h[tid] = 0;
  __syncthreads();
  const int mode = wsi[31];
  const int base = blockIdx.x * 512 + tid;
  atomicAdd(&h[read_id(ids, base, mode)], 1);
  atomicAdd(&h[read_id(ids, base + 256, mode)], 1);
  __syncthreads();
  if (tid < 8 && h[tid]) atomicAdd(&wsi[tid], h[tid]);
}

__global__ void k_scan(int* wsi) {
  if (threadIdx.x == 0) {
    int o = 0, to = 0;
    for (int e = 0; e < NE; ++e) {
      int c = wsi[e];
      wsi[16 + e] = o;   // offs
      wsi[8 + e]  = o;   // cursor
      wsi[40 + e] = to;  // tile offset (256-row tiles)
      o += c;
      to += (c + 255) / 256;
    }
    wsi[16 + NE] = o;
    wsi[40 + NE] = to;
  }
}

// LDS-histogram scatter: per-block base + local rank.
__global__ void k_scatter(const int* __restrict__ ids, int* __restrict__ wsi,
                          int* __restrict__ rowlist) {
  __shared__ int h[8], base[8], c2[8];
  const int tid = threadIdx.x;
  if (tid < 8) { h[tid] = 0; c2[tid] = 0; }
  __syncthreads();
  const int mode = wsi[31];
  const int t = blockIdx.x * 256 + tid;
  const int e = read_id(ids, t, mode);
  atomicAdd(&h[e], 1);
  __syncthreads();
  if (tid < 8 && h[tid]) base[tid] = atomicAdd(&wsi[8 + tid], h[tid]);
  __syncthreads();
  const int r = atomicAdd(&c2[e], 1);
  rowlist[base[e] + r] = t;
}

__global__ void k_cvtH(const float* __restrict__ H, unsigned short* __restrict__ Hb) {
  const int n4 = (MROWS * KD) / 4;
  const int stride = gridDim.x * blockDim.x;
  for (int i = blockIdx.x * blockDim.x + threadIdx.x; i < n4; i += stride) {
    float4v v = ((const float4v*)H)[i];
    ushort4 o;
    o.x = f2bf(v.x); o.y = f2bf(v.y); o.z = f2bf(v.z); o.w = f2bf(v.w);
    ((ushort4*)Hb)[i] = o;
  }
}

// Transpose + convert: W[e][k][n] fp32 -> Wt[e][n][k] bf16 (64x64 tiles).
__global__ void k_cvtW(const float* __restrict__ W, unsigned short* __restrict__ Wt) {
  __shared__ float tile[64][65];
  const int e  = blockIdx.z;
  const int n0 = blockIdx.x * 64;
  const int k0 = blockIdx.y * 64;
  const int tx = threadIdx.x, ty = threadIdx.y;
  const float* Wp = W + (size_t)e * KD * ND;
  #pragma unroll
  for (int i = ty; i < 64; i += 8)
    tile[i][tx] = Wp[(size_t)(k0 + i) * ND + n0 + tx];
  __syncthreads();
  unsigned short* Wo = Wt + (size_t)e * ND * KD;
  #pragma unroll
  for (int i = ty; i < 64; i += 8)
    Wo[(size_t)(n0 + i) * KD + k0 + tx] = f2bf(tile[tx][i]);
}

// Grouped GEMM, 2-phase dbuf, COALESCED staging + chunk-XOR swizzle.
// 256 rows x 256 wcols (128 gate + 128 up interleaved), BK=64, 512 threads
// = 8 waves (2M x 4N), wave tile 128x64, acc[8][4].
// LDS per buffer 64 KiB: A row-major [256][128B] @0, B [256 cols][128B] @32K.
// Staging: thread t covers row t>>3, chunk t&7 -> 8 lanes = one contiguous
// 128B row segment (coalesced). Swizzle: LDS[row][c] holds global chunk
// c^(row&7); reads use c = gk ^ (l15&7) -> bank-conflict-free ds_read_b128.
__global__ __launch_bounds__(512, 2) void k_gemm(
    const unsigned short* __restrict__ Hb, const unsigned short* __restrict__ Wt,
    const int* __restrict__ wsi, const int* __restrict__ rowlist,
    float* __restrict__ Out) {
  const int bid = blockIdx.x;
  const int xcd = bid & 7;
  const int j   = bid >> 3;
  const int colblk = j & 7;        // col-blocks fastest within an XCD
  const int rt  = xcd + (j >> 3) * 8;
  if (rt >= wsi[48]) return;
  int e = 0;
  #pragma unroll
  for (int q = 1; q < 8; ++q)
    if (rt >= wsi[40 + q]) e = q;
  const int cnt = wsi[e];
  const int tile_base = (rt - wsi[40 + e]) * 256;
  const int tile_cnt = min(256, cnt - tile_base);
  const int off = wsi[16 + e] + tile_base;
  const int c0 = colblk * 128;     // out-col base

  __shared__ char lds[131072];
  __shared__ int s_rows[256];

  const int t = threadIdx.x;
  if (t < 256) s_rows[t] = rowlist[off + min(t, tile_cnt - 1)];
  __syncthreads();

  // Staging geometry: sub = row-within-64-group, chunk XOR-preswizzled.
  const int sub = t >> 3;                          // 0..63
  const int chunk = ((t & 7) ^ (sub & 7)) * 16;    // source chunk byte offset
  const char* srcA[4];
  const char* srcB[4];
  {
    const int h_s = sub >> 4, l_s = sub & 15;
    #pragma unroll
    for (int u = 0; u < 4; ++u) {
      const int row_a = u * 64 + sub;
      srcA[u] = (const char*)Hb + (size_t)(s_rows[row_a] >> 1) * (KD * 2) + chunk;
      const int wcol = (h_s < 2) ? (c0 + u * 32 + h_s * 16 + l_s)
                                 : (OUTN + c0 + u * 32 + (h_s - 2) * 16 + l_s);
      srcB[u] = (const char*)Wt + ((size_t)e * ND + wcol) * (KD * 2) + chunk;
    }
  }

  const int lane = t & 63, wid = t >> 6;
  const int wm = wid >> 2, wn = wid & 3;
  const int kc = lane >> 4, l15 = lane & 15;

  f32x4 acc[8][4];
  #pragma unroll
  for (int m = 0; m < 8; ++m)
    #pragma unroll
    for (int h = 0; h < 4; ++h)
      acc[m][h] = (f32x4){0.f, 0.f, 0.f, 0.f};

  // ds_read offsets: row-major [row][128B], chunk index (q*4+kc) ^ (l15&7).
  int aoff[2][8], boff[2][4];
  #pragma unroll
  for (int q = 0; q < 2; ++q) {
    const int cx = ((q * 4 + kc) ^ (l15 & 7)) * 16;
    #pragma unroll
    for (int m = 0; m < 8; ++m)
      aoff[q][m] = (wm * 128 + m * 16 + l15) * 128 + cx;
    #pragma unroll
    for (int h = 0; h < 4; ++h)
      boff[q][h] = 32768 + (wn * 64 + h * 16 + l15) * 128 + cx;
  }

  // Prologue: stage K-tile 0 into buf0.
  #pragma unroll
  for (int u = 0; u < 4; ++u) {
    gload16(srcA[u], lds + t * 16 + u * 8192);
    gload16(srcB[u], lds + 32768 + t * 16 + u * 8192);
  }
  __syncthreads();

  int cur = 0;
  for (int ks = 0; ks < KD / 64; ++ks) {
    if (ks < KD / 64 - 1) {   // prefetch next K-tile into the other buffer
      const int go = (ks + 1) * 128;
      char* nb = lds + (cur ^ 1) * 65536 + t * 16;
      #pragma unroll
      for (int u = 0; u < 4; ++u) {
        gload16(srcA[u] + go, nb + u * 8192);
        gload16(srcB[u] + go, nb + 32768 + u * 8192);
      }
    }
    const char* cb = lds + cur * 65536;
    #pragma unroll
    for (int q = 0; q < 2; ++q) {
      bf16x8 af[8], bfv[4];
      #pragma unroll
      for (int m = 0; m < 8; ++m) af[m] = *(const bf16x8*)(cb + aoff[q][m]);
      #pragma unroll
      for (int h = 0; h < 4; ++h) bfv[h] = *(const bf16x8*)(cb + boff[q][h]);
      #pragma unroll
      for (int m = 0; m < 8; ++m)
        #pragma unroll
        for (int h = 0; h < 4; ++h)
          acc[m][h] = __builtin_amdgcn_mfma_f32_16x16x32_bf16(af[m], bfv[h], acc[m][h], 0, 0, 0);
    }
    __syncthreads();
    cur ^= 1;
  }

  // Fused epilogue: gate = acc[m][h], up = acc[m][h+2], h in {0,1}.
  #pragma unroll
  for (int m = 0; m < 8; ++m) {
    const int rbase = wm * 128 + m * 16 + kc * 4;
    #pragma unroll
    for (int i = 0; i < 4; ++i) {
      const int rl = rbase + i;
      if (rl < tile_cnt) {
        const size_t orow = (size_t)s_rows[rl] * OUTN;
        #pragma unroll
        for (int h = 0; h < 2; ++h) {
          float g = acc[m][h][i];
          float u = acc[m][h + 2][i];
          float s = g / (1.0f + __expf(-g)) * u;
          Out[orow + c0 + wn * 32 + h * 16 + l15] = s;
        }
      }
    }
  }
}

extern "C" void kernel_launch(void* const* d_in, const int* in_sizes, int n_in,
                              void* d_out, int out_size, void* d_ws, size_t ws_size,
                              hipStream_t stream) {
  const float* H  = (const float*)d_in[0];
  const float* W  = (const float*)d_in[1];
  const int* ids  = (const int*)d_in[2];
  float* Out      = (float*)d_out;
  char* ws        = (char*)d_ws;
  int* wsi        = (int*)ws;
  int* rowlist    = (int*)(ws + WS_ROWLIST);
  unsigned short* Hb = (unsigned short*)(ws + WS_HB);
  unsigned short* Wt = (unsigned short*)(ws + WS_WT);

  hipMemsetAsync(ws, 0, 1024, stream);
  k_detect<<<RFLAT / 2 / 256, 256, 0, stream>>>(ids, wsi);
  k_count<<<RFLAT / 512, 256, 0, stream>>>(ids, wsi);
  k_scan<<<1, 64, 0, stream>>>(wsi);
  k_scatter<<<RFLAT / 256, 256, 0, stream>>>(ids, wsi, rowlist);
  k_cvtH<<<2048, 256, 0, stream>>>(H, Hb);
  k_cvtW<<<dim3(ND / 64, KD / 64, NE), dim3(64, 8), 0, stream>>>(W, Wt);
  // rowtiles (256-row) <= 135; 17 slots per XCD x 8 XCDs x 8 colblocks
  k_gemm<<<8 * 17 * 8, 512, 0, stream>>>(Hb, Wt, wsi, rowlist, Out);
}